// Round 2
// baseline (325.625 us; speedup 1.0000x reference)
//
#include <hip/hip_runtime.h>

#define N1c 25000
#define N2c 5000
#define Dc 256
#define DOUTc 128
#define EPSc 1e-5f
#define NEGc 0.01f
#define CAPc 32            // bucket capacity; passing degree ~Poisson(3.2)

typedef __attribute__((ext_vector_type(8))) short short8;
typedef __attribute__((ext_vector_type(4))) float f32x4;

__device__ __forceinline__ ushort f2bf(float f) {
    unsigned u = __float_as_uint(f);
    u += 0x7fffu + ((u >> 16) & 1u);          // round-to-nearest-even
    return (ushort)(u >> 16);
}
__device__ __forceinline__ float bf2f(ushort u) {
    return __uint_as_float(((unsigned)u) << 16);
}

// ---- prep_fill: weight transpose + single-pass bucketed CSR + mask1 --------
// cnt0/cnt1 pre-zeroed by hipMemsetAsync. One pass over each edge list:
// pos = atomicAdd(cnt[dst]); pos < CAP -> slot store. cnt keeps TRUE degree
// (may exceed CAP); fused gather falls back to an edge rescan in that
// (never-hit) case, so the mean divisor is always the true passing degree.
__global__ __launch_bounds__(256) void prep_fill(
    const int* __restrict__ src0, const int* __restrict__ dst0, const int* __restrict__ val0,
    const int* __restrict__ src1, const int* __restrict__ dst1, const int* __restrict__ val1,
    const int* __restrict__ ts, const int* __restrict__ time_p, const int* __restrict__ itv_p,
    const float* __restrict__ W1l, const float* __restrict__ W1r,
    const float* __restrict__ W2l, const float* __restrict__ W2r,
    int E0, int E1,
    ushort* __restrict__ Bt1, ushort* __restrict__ Bt2,
    int* __restrict__ cnt0, int* __restrict__ cnt1,
    int* __restrict__ eidx0, int* __restrict__ eidx1,
    float* __restrict__ mask_out) {
    const int flat = blockIdx.x * blockDim.x + threadIdx.x;
    const int NT = gridDim.x * blockDim.x;
    const int t0 = *time_p, iv = *itv_p;

    for (int i = flat; i < 256 * 512; i += NT) {   // Bt1 [n][512]
        int n = i >> 9, k = i & 511;
        float v = (k < 256) ? W1l[(size_t)k * 256 + n] : W1r[(size_t)(k - 256) * 256 + n];
        Bt1[i] = f2bf(v);
    }
    for (int i = flat; i < 128 * 512; i += NT) {   // Bt2 [n][512]
        int n = i >> 9, k = i & 511;
        float v = (k < 256) ? W2l[(size_t)k * 128 + n] : W2r[(size_t)(k - 256) * 128 + n];
        Bt2[i] = f2bf(v);
    }
    for (int e = flat; e < E0; e += NT) {
        int t = ts[val0[e]];
        if (t >= t0 && t < t0 + iv) {
            int d = dst0[e];
            int pos = atomicAdd(&cnt0[d], 1);
            if (pos < CAPc) eidx0[d * CAPc + pos] = src0[e];
        }
    }
    for (int e = flat; e < E1; e += NT) {
        int t = ts[val1[e]];
        bool m = (t >= t0 && t < t0 + iv);
        mask_out[e] = m ? 1.0f : 0.0f;
        if (m) {
            int d = dst1[e];
            int pos = atomicAdd(&cnt1[d], 1);
            if (pos < CAPc) eidx1[d * CAPc + pos] = src1[e];
        }
    }
}

// ---- fused gather + GEMM ---------------------------------------------------
// Block = 128 thr (2 waves), BM = 32 rows, full N in one block (NJ col-tiles).
// Phase 1: each wave gathers its 16 A-rows (bucketed mean + root row) into
//          LDS As[32][536] as bf16 covering K=512 ([agg | root]).
// Phase 2: barrier-free k-loop: A-fragments from LDS, B-fragments DIRECT from
//          global (Bt is L2-resident: 256/128 KB), MFMA accumulate.
// VARIANT 0: gather/root from fp32 x, out = bf16 h with BN+leaky epilogue.
// VARIANT 1: gather/root from bf16 h, out = fp32 + bias.
// As stride 536 ushorts = 268 dwords == 12 mod 32 -> b128 fragment reads
// spread across all 8 bank groups (balanced, effectively conflict-free).
template <int VARIANT, int NJ>
__global__ __launch_bounds__(128) void fused_gemm(
    const void* __restrict__ Asrc,
    const int* __restrict__ cnt, const int* __restrict__ eidx,
    const int* __restrict__ src, const int* __restrict__ dst,
    const int* __restrict__ val, const int* __restrict__ ts,
    const int* __restrict__ time_p, const int* __restrict__ itv_p, int E,
    const ushort* __restrict__ Bt,
    const float* __restrict__ bias,
    const float* __restrict__ g, const float* __restrict__ bt,
    const float* __restrict__ rm, const float* __restrict__ rv,
    void* __restrict__ Cout, int M) {
    __shared__ ushort As[32][536];
    const int tid = threadIdx.x;
    const int wave = tid >> 6, lane = tid & 63;
    const int quad = lane >> 4, l16 = lane & 15;
    const int m0 = blockIdx.x * 32;
    const float* Xf = (const float*)Asrc;
    const ushort* Hb = (const ushort*)Asrc;

    // ---------------- phase 1: gather 16 rows per wave ----------------
    for (int r8 = 0; r8 < 16; ++r8) {
        int r = wave * 16 + r8;
        int m = m0 + r;
        if (m >= M) {
            *(ushort4*)&As[r][lane * 4] = make_ushort4(0, 0, 0, 0);
            *(ushort4*)&As[r][256 + lane * 4] = make_ushort4(0, 0, 0, 0);
            continue;
        }
        int c = cnt[m];
        int my = (lane < CAPc) ? eidx[m * CAPc + lane] : 0;   // always issued: breaks dep on c
        float4 a0 = make_float4(0.f, 0.f, 0.f, 0.f);
        float4 a1 = make_float4(0.f, 0.f, 0.f, 0.f);
        if (c <= CAPc) {
            int j = 0;
            for (; j + 1 < c; j += 2) {
                int s0 = __shfl(my, j, 64);
                int s1 = __shfl(my, j + 1, 64);
                if (VARIANT == 0) {
                    float4 v0 = *(const float4*)(Xf + (size_t)s0 * Dc + lane * 4);
                    float4 v1 = *(const float4*)(Xf + (size_t)s1 * Dc + lane * 4);
                    a0.x += v0.x; a0.y += v0.y; a0.z += v0.z; a0.w += v0.w;
                    a1.x += v1.x; a1.y += v1.y; a1.z += v1.z; a1.w += v1.w;
                } else {
                    ushort4 v0 = *(const ushort4*)(Hb + (size_t)s0 * Dc + lane * 4);
                    ushort4 v1 = *(const ushort4*)(Hb + (size_t)s1 * Dc + lane * 4);
                    a0.x += bf2f(v0.x); a0.y += bf2f(v0.y); a0.z += bf2f(v0.z); a0.w += bf2f(v0.w);
                    a1.x += bf2f(v1.x); a1.y += bf2f(v1.y); a1.z += bf2f(v1.z); a1.w += bf2f(v1.w);
                }
            }
            if (j < c) {
                int s0 = __shfl(my, j, 64);
                if (VARIANT == 0) {
                    float4 v0 = *(const float4*)(Xf + (size_t)s0 * Dc + lane * 4);
                    a0.x += v0.x; a0.y += v0.y; a0.z += v0.z; a0.w += v0.w;
                } else {
                    ushort4 v0 = *(const ushort4*)(Hb + (size_t)s0 * Dc + lane * 4);
                    a0.x += bf2f(v0.x); a0.y += bf2f(v0.y); a0.z += bf2f(v0.z); a0.w += bf2f(v0.w);
                }
            }
        } else {
            // overflow fallback (statistically never taken; keeps any input correct)
            int t0 = *time_p, iv = *itv_p;
            for (int e = 0; e < E; ++e) {
                if (dst[e] != m) continue;
                int t = ts[val[e]];
                if (t >= t0 && t < t0 + iv) {
                    if (VARIANT == 0) {
                        float4 v = *(const float4*)(Xf + (size_t)src[e] * Dc + lane * 4);
                        a0.x += v.x; a0.y += v.y; a0.z += v.z; a0.w += v.w;
                    } else {
                        ushort4 v = *(const ushort4*)(Hb + (size_t)src[e] * Dc + lane * 4);
                        a0.x += bf2f(v.x); a0.y += bf2f(v.y); a0.z += bf2f(v.z); a0.w += bf2f(v.w);
                    }
                }
            }
        }
        a0.x += a1.x; a0.y += a1.y; a0.z += a1.z; a0.w += a1.w;
        float inv = 1.0f / fmaxf((float)c, 1.0f);
        ushort4 o;
        o.x = f2bf(a0.x * inv); o.y = f2bf(a0.y * inv);
        o.z = f2bf(a0.z * inv); o.w = f2bf(a0.w * inv);
        *(ushort4*)&As[r][lane * 4] = o;
        // root row (self features)
        if (VARIANT == 0) {
            float4 rt = *(const float4*)(Xf + (size_t)m * Dc + lane * 4);
            ushort4 ro;
            ro.x = f2bf(rt.x); ro.y = f2bf(rt.y); ro.z = f2bf(rt.z); ro.w = f2bf(rt.w);
            *(ushort4*)&As[r][256 + lane * 4] = ro;
        } else {
            *(ushort4*)&As[r][256 + lane * 4] = *(const ushort4*)(Hb + (size_t)m * Dc + lane * 4);
        }
    }
    __syncthreads();

    // ---------------- phase 2: barrier-free MFMA k-loop ----------------
    f32x4 acc[NJ] = {};
    const ushort* Bw = Bt + (size_t)l16 * 512 + quad * 8;
    for (int k0 = 0; k0 < 512; k0 += 32) {
        short8 af = *(const short8*)&As[wave * 16 + l16][k0 + quad * 8];
        uint4 bfr[NJ];
#pragma unroll
        for (int j = 0; j < NJ; ++j)
            bfr[j] = *(const uint4*)(Bw + (size_t)j * 16 * 512 + k0);
#pragma unroll
        for (int j = 0; j < NJ; ++j) {
            short8 bf = *reinterpret_cast<const short8*>(&bfr[j]);
            acc[j] = __builtin_amdgcn_mfma_f32_16x16x32_bf16(af, bf, acc[j], 0, 0, 0);
        }
    }

    // ---------------- epilogue: C/D layout col=l16, row=quad*4+reg -----
#pragma unroll
    for (int j = 0; j < NJ; ++j) {
        int gn = j * 16 + l16;
        float sc = 1.f, sh = bias[gn];
        if (VARIANT == 0) {
            float s = g[gn] * rsqrtf(rv[gn] + EPSc);
            sh = (bias[gn] - rm[gn]) * s + bt[gn];
            sc = s;
        }
        int gmb = m0 + wave * 16 + quad * 4;
#pragma unroll
        for (int rr = 0; rr < 4; ++rr) {
            int gm = gmb + rr;
            if (gm >= M) continue;
            float v = acc[j][rr];
            if (VARIANT == 0) {
                v = v * sc + sh;
                v = v >= 0.f ? v : NEGc * v;
                ((ushort*)Cout)[(size_t)gm * Dc + gn] = f2bf(v);
            } else {
                ((float*)Cout)[(size_t)gm * DOUTc + gn] = v + sh;
            }
        }
    }
}

extern "C" void kernel_launch(void* const* d_in, const int* in_sizes, int n_in,
                              void* d_out, int out_size, void* d_ws, size_t ws_size,
                              hipStream_t stream) {
    const float* x    = (const float*)d_in[0];
    const int* src0   = (const int*)d_in[1];
    const int* dst0   = (const int*)d_in[2];
    const int* val0   = (const int*)d_in[3];
    const int* src1   = (const int*)d_in[4];
    const int* dst1   = (const int*)d_in[5];
    const int* val1   = (const int*)d_in[6];
    const int* ts     = (const int*)d_in[7];
    const int* time_p = (const int*)d_in[8];
    const int* itv_p  = (const int*)d_in[9];
    const float* W1l  = (const float*)d_in[10];
    const float* W1r  = (const float*)d_in[11];
    const float* b1   = (const float*)d_in[12];
    const float* g1   = (const float*)d_in[13];
    const float* bt1  = (const float*)d_in[14];
    const float* rm1  = (const float*)d_in[15];
    const float* rv1  = (const float*)d_in[16];
    const float* W2l  = (const float*)d_in[17];
    const float* W2r  = (const float*)d_in[18];
    const float* b2   = (const float*)d_in[19];
    int E0 = in_sizes[1];
    int E1 = in_sizes[4];
    float* out = (float*)d_out;

    // ---- workspace layout ----
    ushort* h    = (ushort*)d_ws;                  // [N1][256] bf16
    ushort* Bt1  = h    + (size_t)N1c * Dc;        // [256][512]
    ushort* Bt2  = Bt1  + 256 * 512;               // [128][512]
    int* ip      = (int*)(Bt2 + 128 * 512);
    int* cnt0    = ip;             ip += N1c;      // -- zeroed (memset)
    int* cnt1    = ip;             ip += N2c;      // -- zeroed (memset)
    int* eidx0   = ip;             ip += N1c * CAPc;
    int* eidx1   = ip;             ip += N2c * CAPc;
    float* mask_tail = out + (size_t)N2c * DOUTc;

    hipMemsetAsync(cnt0, 0, (size_t)(N1c + N2c) * sizeof(int), stream);

    prep_fill<<<2048, 256, 0, stream>>>(
        src0, dst0, val0, src1, dst1, val1, ts, time_p, itv_p,
        W1l, W1r, W2l, W2r, E0, E1, Bt1, Bt2,
        cnt0, cnt1, eidx0, eidx1, mask_tail);
    fused_gemm<0, 16><<<(N1c + 31) / 32, 128, 0, stream>>>(
        x, cnt0, eidx0, src0, dst0, val0, ts, time_p, itv_p, E0,
        Bt1, b1, g1, bt1, rm1, rv1, h, N1c);
    fused_gemm<1, 8><<<(N2c + 31) / 32, 128, 0, stream>>>(
        h, cnt1, eidx1, src1, dst1, val1, ts, time_p, itv_p, E1,
        Bt2, b2, nullptr, nullptr, nullptr, nullptr, out, N2c);
}

// Round 3
// 248.668 us; speedup vs baseline: 1.3095x; 1.3095x over previous
//
#include <hip/hip_runtime.h>

#define N1c 25000
#define N2c 5000
#define Dc 256
#define DOUTc 128
#define EPSc 1e-5f
#define NEGc 0.01f
#define CAPc 32            // bucket capacity; passing degree ~Poisson(3.2)

typedef __attribute__((ext_vector_type(8))) short short8;
typedef __attribute__((ext_vector_type(4))) float f32x4;

__device__ __forceinline__ ushort f2bf(float f) {
    unsigned u = __float_as_uint(f);
    u += 0x7fffu + ((u >> 16) & 1u);          // round-to-nearest-even
    return (ushort)(u >> 16);
}
__device__ __forceinline__ float bf2f(ushort u) {
    return __uint_as_float(((unsigned)u) << 16);
}

// ---- prep_fill: weight transpose + single-pass bucketed CSR + mask1 --------
// cnt0/cnt1 pre-zeroed by hipMemsetAsync. One pass over each edge list:
// pos = atomicAdd(cnt[dst]); pos < CAP -> slot store. cnt keeps TRUE degree
// (may exceed CAP); fused gather falls back to an edge rescan in that
// (never-hit) case, so the mean divisor is always the true passing degree.
__global__ __launch_bounds__(256) void prep_fill(
    const int* __restrict__ src0, const int* __restrict__ dst0, const int* __restrict__ val0,
    const int* __restrict__ src1, const int* __restrict__ dst1, const int* __restrict__ val1,
    const int* __restrict__ ts, const int* __restrict__ time_p, const int* __restrict__ itv_p,
    const float* __restrict__ W1l, const float* __restrict__ W1r,
    const float* __restrict__ W2l, const float* __restrict__ W2r,
    int E0, int E1,
    ushort* __restrict__ Bt1, ushort* __restrict__ Bt2,
    int* __restrict__ cnt0, int* __restrict__ cnt1,
    int* __restrict__ eidx0, int* __restrict__ eidx1,
    float* __restrict__ mask_out) {
    const int flat = blockIdx.x * blockDim.x + threadIdx.x;
    const int NT = gridDim.x * blockDim.x;
    const int t0 = *time_p, iv = *itv_p;

    for (int i = flat; i < 256 * 512; i += NT) {   // Bt1 [n][512]
        int n = i >> 9, k = i & 511;
        float v = (k < 256) ? W1l[(size_t)k * 256 + n] : W1r[(size_t)(k - 256) * 256 + n];
        Bt1[i] = f2bf(v);
    }
    for (int i = flat; i < 128 * 512; i += NT) {   // Bt2 [n][512]
        int n = i >> 9, k = i & 511;
        float v = (k < 256) ? W2l[(size_t)k * 128 + n] : W2r[(size_t)(k - 256) * 128 + n];
        Bt2[i] = f2bf(v);
    }
    for (int e = flat; e < E0; e += NT) {
        int t = ts[val0[e]];
        if (t >= t0 && t < t0 + iv) {
            int d = dst0[e];
            int pos = atomicAdd(&cnt0[d], 1);
            if (pos < CAPc) eidx0[d * CAPc + pos] = src0[e];
        }
    }
    for (int e = flat; e < E1; e += NT) {
        int t = ts[val1[e]];
        bool m = (t >= t0 && t < t0 + iv);
        mask_out[e] = m ? 1.0f : 0.0f;
        if (m) {
            int d = dst1[e];
            int pos = atomicAdd(&cnt1[d], 1);
            if (pos < CAPc) eidx1[d * CAPc + pos] = src1[e];
        }
    }
}

// ---- fused gather + GEMM, 8-wave blocks ------------------------------------
// Block = 512 thr (8 waves), BMT rows, full N per block (8*NJW col-tiles).
// Phase 1: each wave gathers BMT/8 A-rows (bucketed mean + root row) into
//          LDS As[BMT][536] as bf16 covering K=512 ([agg | root]).
// Phase 2: barrier-free k-loop: A-fragments from LDS, B-fragments DIRECT from
//          global (Bt is L2-resident: 256/128 KB). Wave w owns col-tiles
//          w*NJW .. w*NJW+NJW-1; RT=BMT/16 row-tiles; acc[RT][NJW] (<=16 VGPR).
// VARIANT 0: gather/root from fp32 x, out = bf16 h with BN+leaky epilogue.
// VARIANT 1: gather/root from bf16 h, out = fp32 + bias.
// As stride 536 ushorts = 268 dwords == 12 mod 32 -> the 8 row-bases tile all
// 32 banks; wave64 b128 reads are 2-lanes/bank = free.
template <int VARIANT, int BMT, int NJW>
__global__ __launch_bounds__(512) void fused_gemm(
    const void* __restrict__ Asrc,
    const int* __restrict__ cnt, const int* __restrict__ eidx,
    const int* __restrict__ src, const int* __restrict__ dst,
    const int* __restrict__ val, const int* __restrict__ ts,
    const int* __restrict__ time_p, const int* __restrict__ itv_p, int E,
    const ushort* __restrict__ Bt,
    const float* __restrict__ bias,
    const float* __restrict__ g, const float* __restrict__ bt,
    const float* __restrict__ rm, const float* __restrict__ rv,
    void* __restrict__ Cout, int M) {
    constexpr int RT = BMT / 16;          // row-tiles per block
    constexpr int RPW = BMT / 8;          // gather rows per wave
    __shared__ ushort As[BMT][536];
    const int tid = threadIdx.x;
    const int wave = tid >> 6, lane = tid & 63;
    const int quad = lane >> 4, l16 = lane & 15;
    const int m0 = blockIdx.x * BMT;
    const float* Xf = (const float*)Asrc;
    const ushort* Hb = (const ushort*)Asrc;

    // ---------------- phase 1: gather RPW rows per wave ----------------
    for (int i = 0; i < RPW; ++i) {
        int r = wave * RPW + i;
        int m = m0 + r;
        if (m >= M) {
            *(ushort4*)&As[r][lane * 4] = make_ushort4(0, 0, 0, 0);
            *(ushort4*)&As[r][256 + lane * 4] = make_ushort4(0, 0, 0, 0);
            continue;
        }
        int c = cnt[m];
        int my = (lane < CAPc) ? eidx[m * CAPc + lane] : 0;   // always issued
        float4 a0 = make_float4(0.f, 0.f, 0.f, 0.f);
        float4 a1 = make_float4(0.f, 0.f, 0.f, 0.f);
        if (c <= CAPc) {
            int j = 0;
            for (; j + 1 < c; j += 2) {
                int s0 = __shfl(my, j, 64);
                int s1 = __shfl(my, j + 1, 64);
                if (VARIANT == 0) {
                    float4 v0 = *(const float4*)(Xf + (size_t)s0 * Dc + lane * 4);
                    float4 v1 = *(const float4*)(Xf + (size_t)s1 * Dc + lane * 4);
                    a0.x += v0.x; a0.y += v0.y; a0.z += v0.z; a0.w += v0.w;
                    a1.x += v1.x; a1.y += v1.y; a1.z += v1.z; a1.w += v1.w;
                } else {
                    ushort4 v0 = *(const ushort4*)(Hb + (size_t)s0 * Dc + lane * 4);
                    ushort4 v1 = *(const ushort4*)(Hb + (size_t)s1 * Dc + lane * 4);
                    a0.x += bf2f(v0.x); a0.y += bf2f(v0.y); a0.z += bf2f(v0.z); a0.w += bf2f(v0.w);
                    a1.x += bf2f(v1.x); a1.y += bf2f(v1.y); a1.z += bf2f(v1.z); a1.w += bf2f(v1.w);
                }
            }
            if (j < c) {
                int s0 = __shfl(my, j, 64);
                if (VARIANT == 0) {
                    float4 v0 = *(const float4*)(Xf + (size_t)s0 * Dc + lane * 4);
                    a0.x += v0.x; a0.y += v0.y; a0.z += v0.z; a0.w += v0.w;
                } else {
                    ushort4 v0 = *(const ushort4*)(Hb + (size_t)s0 * Dc + lane * 4);
                    a0.x += bf2f(v0.x); a0.y += bf2f(v0.y); a0.z += bf2f(v0.z); a0.w += bf2f(v0.w);
                }
            }
        } else {
            // overflow fallback (statistically never taken; keeps any input correct)
            int t0 = *time_p, iv = *itv_p;
            for (int e = 0; e < E; ++e) {
                if (dst[e] != m) continue;
                int t = ts[val[e]];
                if (t >= t0 && t < t0 + iv) {
                    if (VARIANT == 0) {
                        float4 v = *(const float4*)(Xf + (size_t)src[e] * Dc + lane * 4);
                        a0.x += v.x; a0.y += v.y; a0.z += v.z; a0.w += v.w;
                    } else {
                        ushort4 v = *(const ushort4*)(Hb + (size_t)src[e] * Dc + lane * 4);
                        a0.x += bf2f(v.x); a0.y += bf2f(v.y); a0.z += bf2f(v.z); a0.w += bf2f(v.w);
                    }
                }
            }
        }
        a0.x += a1.x; a0.y += a1.y; a0.z += a1.z; a0.w += a1.w;
        float inv = 1.0f / fmaxf((float)c, 1.0f);
        ushort4 o;
        o.x = f2bf(a0.x * inv); o.y = f2bf(a0.y * inv);
        o.z = f2bf(a0.z * inv); o.w = f2bf(a0.w * inv);
        *(ushort4*)&As[r][lane * 4] = o;
        // root row (self features)
        if (VARIANT == 0) {
            float4 rt = *(const float4*)(Xf + (size_t)m * Dc + lane * 4);
            ushort4 ro;
            ro.x = f2bf(rt.x); ro.y = f2bf(rt.y); ro.z = f2bf(rt.z); ro.w = f2bf(rt.w);
            *(ushort4*)&As[r][256 + lane * 4] = ro;
        } else {
            *(ushort4*)&As[r][256 + lane * 4] = *(const ushort4*)(Hb + (size_t)m * Dc + lane * 4);
        }
    }
    __syncthreads();

    // ---------------- phase 2: barrier-free MFMA k-loop ----------------
    f32x4 acc[RT][NJW] = {};
    const ushort* Bw = Bt + (size_t)((wave * NJW) * 16 + l16) * 512 + quad * 8;
    for (int k0 = 0; k0 < 512; k0 += 32) {
        short8 af[RT];
#pragma unroll
        for (int rt = 0; rt < RT; ++rt)
            af[rt] = *(const short8*)&As[rt * 16 + l16][k0 + quad * 8];
        uint4 bfr[NJW];
#pragma unroll
        for (int jj = 0; jj < NJW; ++jj)
            bfr[jj] = *(const uint4*)(Bw + (size_t)jj * 16 * 512 + k0);
#pragma unroll
        for (int jj = 0; jj < NJW; ++jj) {
            short8 bf = *reinterpret_cast<const short8*>(&bfr[jj]);
#pragma unroll
            for (int rt = 0; rt < RT; ++rt)
                acc[rt][jj] = __builtin_amdgcn_mfma_f32_16x16x32_bf16(af[rt], bf, acc[rt][jj], 0, 0, 0);
        }
    }

    // ---------------- epilogue: C/D layout col=l16, row=quad*4+reg -----
#pragma unroll
    for (int jj = 0; jj < NJW; ++jj) {
        int gn = (wave * NJW + jj) * 16 + l16;
        float sc = 1.f, sh = bias[gn];
        if (VARIANT == 0) {
            float s = g[gn] * rsqrtf(rv[gn] + EPSc);
            sh = (bias[gn] - rm[gn]) * s + bt[gn];
            sc = s;
        }
#pragma unroll
        for (int rt = 0; rt < RT; ++rt) {
            int gmb = m0 + rt * 16 + quad * 4;
#pragma unroll
            for (int rr = 0; rr < 4; ++rr) {
                int gm = gmb + rr;
                if (gm >= M) continue;
                float v = acc[rt][jj][rr];
                if (VARIANT == 0) {
                    v = v * sc + sh;
                    v = v >= 0.f ? v : NEGc * v;
                    ((ushort*)Cout)[(size_t)gm * Dc + gn] = f2bf(v);
                } else {
                    ((float*)Cout)[(size_t)gm * DOUTc + gn] = v + sh;
                }
            }
        }
    }
}

extern "C" void kernel_launch(void* const* d_in, const int* in_sizes, int n_in,
                              void* d_out, int out_size, void* d_ws, size_t ws_size,
                              hipStream_t stream) {
    const float* x    = (const float*)d_in[0];
    const int* src0   = (const int*)d_in[1];
    const int* dst0   = (const int*)d_in[2];
    const int* val0   = (const int*)d_in[3];
    const int* src1   = (const int*)d_in[4];
    const int* dst1   = (const int*)d_in[5];
    const int* val1   = (const int*)d_in[6];
    const int* ts     = (const int*)d_in[7];
    const int* time_p = (const int*)d_in[8];
    const int* itv_p  = (const int*)d_in[9];
    const float* W1l  = (const float*)d_in[10];
    const float* W1r  = (const float*)d_in[11];
    const float* b1   = (const float*)d_in[12];
    const float* g1   = (const float*)d_in[13];
    const float* bt1  = (const float*)d_in[14];
    const float* rm1  = (const float*)d_in[15];
    const float* rv1  = (const float*)d_in[16];
    const float* W2l  = (const float*)d_in[17];
    const float* W2r  = (const float*)d_in[18];
    const float* b2   = (const float*)d_in[19];
    int E0 = in_sizes[1];
    int E1 = in_sizes[4];
    float* out = (float*)d_out;

    // ---- workspace layout ----
    ushort* h    = (ushort*)d_ws;                  // [N1][256] bf16
    ushort* Bt1  = h    + (size_t)N1c * Dc;        // [256][512]
    ushort* Bt2  = Bt1  + 256 * 512;               // [128][512]
    int* ip      = (int*)(Bt2 + 128 * 512);
    int* cnt0    = ip;             ip += N1c;      // -- zeroed (memset)
    int* cnt1    = ip;             ip += N2c;      // -- zeroed (memset)
    int* eidx0   = ip;             ip += N1c * CAPc;
    int* eidx1   = ip;             ip += N2c * CAPc;
    float* mask_tail = out + (size_t)N2c * DOUTc;

    hipMemsetAsync(cnt0, 0, (size_t)(N1c + N2c) * sizeof(int), stream);

    prep_fill<<<2048, 256, 0, stream>>>(
        src0, dst0, val0, src1, dst1, val1, ts, time_p, itv_p,
        W1l, W1r, W2l, W2r, E0, E1, Bt1, Bt2,
        cnt0, cnt1, eidx0, eidx1, mask_tail);
    fused_gemm<0, 32, 2><<<(N1c + 31) / 32, 512, 0, stream>>>(
        x, cnt0, eidx0, src0, dst0, val0, ts, time_p, itv_p, E0,
        Bt1, b1, g1, bt1, rm1, rv1, h, N1c);
    fused_gemm<1, 16, 1><<<(N2c + 15) / 16, 512, 0, stream>>>(
        h, cnt1, eidx1, src1, dst1, val1, ts, time_p, itv_p, E1,
        Bt2, b2, nullptr, nullptr, nullptr, nullptr, out, N2c);
}